// Round 15
// baseline (960.693 us; speedup 1.0000x reference)
//
#include <hip/hip_runtime.h>
#include <hip/hip_bf16.h>

// B=256, LATENT=64, HID=256, OUT=128, S=512. gates [i|f|g|o] -> 4H=1024.
//
// R20: R19 + outproj FUSED into lstm_main as a per-block epilogue.
// Every block owns all hs rows it wrote (2 batch rows x 512 t; all 256 cols
// come from its own lanes) -> projection needs only a block-local
// vmcnt(0)+barrier, no grid sync. 8 tiles x {stage 128 (b,t)-rows -> LDS,
// MFMA vs pre-converted owb frags, fp32 store in place}. hs row bytes
// (256 bf16) == out row bytes (128 fp32) -> per-tile in-place safe (R18's
// validated outproj logic, relocated). Kills the 64MB hs re-read through a
// separate launch (~55us -> ~10us absorbed).
// lstm loop = R17/R19 exactly: 128 blocks x 2 rows x 512 thr; 40 reg +
// 13 LDS + 11 stream weight frags (placement bracketed: 44 spills);
// A row=l15&1 dataflow; literal-index+cndmask extraction; xp_own add;
// lgkm-only barrier. hA [2][16*STR] rows 0,1 live; STR=264.

typedef __bf16 v8bf __attribute__((ext_vector_type(8)));
typedef float  v4f  __attribute__((ext_vector_type(4)));

__device__ __forceinline__ float sigmoidf_(float x) {
    return __builtin_amdgcn_rcpf(1.0f + __expf(-x));
}
__device__ __forceinline__ float tanhf_(float x) {
    float ax = fabsf(x);
    float e  = __expf(-2.0f * ax);
    float t  = (1.0f - e) * __builtin_amdgcn_rcpf(1.0f + e);
    return copysignf(t, x);
}

// ---- wbf2 layout: frag FR(wv,jt,g,ks) = ((wv*2+jt)*4+g)*8+ks, 1024 B each;
// lane l holds 16 B at FR*1024 + l*16 = w_hh[g*256+wv*32+jt*16+(l&15)][ks*32+(l>>4)*8 + 0..7]
__global__ void cvt_kernel(const float* __restrict__ w, uint4* __restrict__ o) {
    const int gg = blockIdx.x * 256 + threadIdx.x;    // 0..32767
    const int F = gg >> 6, l = gg & 63;
    const int wv = F >> 6, rem = F & 63;
    const int jt = rem >> 5, g4 = (rem >> 3) & 3, ks = rem & 7;
    const int row = g4 * 256 + wv * 32 + jt * 16 + (l & 15);
    const int col = ks * 32 + (l >> 4) * 8;
    const float4 a = *(const float4*)(w + row * 256 + col);
    const float4 b = *(const float4*)(w + row * 256 + col + 4);
    union { __hip_bfloat16 h[8]; uint4 u; } p;
    p.h[0] = __float2bfloat16(a.x); p.h[1] = __float2bfloat16(a.y);
    p.h[2] = __float2bfloat16(a.z); p.h[3] = __float2bfloat16(a.w);
    p.h[4] = __float2bfloat16(b.x); p.h[5] = __float2bfloat16(b.y);
    p.h[6] = __float2bfloat16(b.z); p.h[7] = __float2bfloat16(b.w);
    o[gg] = p.u;
}

// ---- owb layout: frag F(nt,ks) = nt*8+ks, 1024 B each; lane l holds
// out_w[nt*16+(l&15)][ks*32+(l>>4)*8 + 0..7] -> epilogue B-operand direct.
__global__ void cvt_ow(const float* __restrict__ w, uint4* __restrict__ o) {
    const int gg = blockIdx.x * 256 + threadIdx.x;    // 0..4095
    const int F = gg >> 6, l = gg & 63;
    const int nt = F >> 3, ks = F & 7;
    const int row = nt * 16 + (l & 15);
    const int col = ks * 32 + (l >> 4) * 8;
    const float4 a = *(const float4*)(w + row * 256 + col);
    const float4 b = *(const float4*)(w + row * 256 + col + 4);
    union { __hip_bfloat16 h[8]; uint4 u; } p;
    p.h[0] = __float2bfloat16(a.x); p.h[1] = __float2bfloat16(a.y);
    p.h[2] = __float2bfloat16(a.z); p.h[3] = __float2bfloat16(a.w);
    p.h[4] = __float2bfloat16(b.x); p.h[5] = __float2bfloat16(b.y);
    p.h[6] = __float2bfloat16(b.z); p.h[7] = __float2bfloat16(b.w);
    o[gg] = p.u;
}

constexpr int STR = 264;                 // hA / tile row stride (bf16 elems)

// jt==1 weight source tables: kind 0=reg,1=lds,2=stream  (R17 placement)
// jt1 frag offsets 0..31 = g*8+ks.
//   reg:    offsets 0..7  (g0 all)            -> wreg 32..39
//   LDS:    offsets 8..20 (g1 all, g2 ks0..4) -> slots 0..12
//   stream: offsets 21..31 (g2 ks5..7, g3 all)
__device__ constexpr int K1[4][8] = {
    {0,0,0,0, 0,0,0,0},
    {1,1,1,1, 1,1,1,1},
    {1,1,1,1, 1,2,2,2},
    {2,2,2,2, 2,2,2,2},
};
__device__ constexpr int X1[4][8] = {
    {32,33,34,35, 36,37,38,39},
    { 0, 1, 2, 3,  4, 5, 6, 7},
    { 8, 9,10,11, 12, 0, 0, 0},
    { 0, 0, 0, 0,  0, 0, 0, 0},
};

__global__ __launch_bounds__(512, 2) void lstm_main(
    const float* __restrict__ z,     const float* __restrict__ fc_w,
    const float* __restrict__ fc_b,  const float* __restrict__ w_ih,
    const float* __restrict__ b_ih,  const float* __restrict__ b_hh,
    const __hip_bfloat16* __restrict__ wbf2,
    const __hip_bfloat16* __restrict__ owb,
    const float* __restrict__ out_b,
    __hip_bfloat16* __restrict__ hsb)           // = d_out viewed as bf16 [B*512][256]
{
    __shared__ __align__(16) unsigned char SM[16896 + 139264];
    __hip_bfloat16* hA = (__hip_bfloat16*)SM;             // [2][16*STR]
    unsigned char*  WL = SM + 16896;                      // weight LDS / prologue / tile alias

    const int tid  = threadIdx.x;
    const int wv   = tid >> 6;       // 0..7
    const int lane = tid & 63;
    const int l15  = lane & 15;
    const int quad = lane >> 4;
    const int b_base = blockIdx.x * 2;                    // 2 batch rows / block

    // ownership: lane handles exactly 1 h-elem (row rb, col mycol), jt=quad>>1
    const int rb    = quad & 1;                           // even quads row 0, odd row 1
    const int myjt  = quad >> 1;
    const int mycol = wv * 32 + myjt * 16 + l15;

    // ================= prologue (aliased LDS) =================
    float* h0f = (float*)WL;               // [2][256]   2 KB used
    float* xps = (float*)(WL + 16384);     // [2][1024]  8 KB used
    float* zt  = (float*)(WL + 81920);     // [2][64]   0.5 KB used

    {   // z tile: 2 rows x 64 (hA rows 2..15 are dead -> no zero-init needed)
        if (tid < 128) zt[tid] = z[b_base * 64 + tid];
    }
    __syncthreads();

    {   // h0 = z @ fc_w.T + fc_b  (fp32 exact). thread: col=tid&255, row=tid>>8
        const int col = tid & 255;
        const int r   = tid >> 8;                         // 0 or 1
        float a = fc_b[col];
        for (int k = 0; k < 64; k += 4) {
            const float4 w = *(const float4*)(fc_w + col * 64 + k);
            const float4 h = *(const float4*)(zt + r * 64 + k);
            a += w.x * h.x + w.y * h.y + w.z * h.z + w.w * h.w;
        }
        h0f[r * 256 + col] = a;
        hA[r * STR + col] = __float2bfloat16(a);
    }
    __syncthreads();

    {   // x_proj = h0 @ w_ih.T + (b_ih + b_hh)  (fp32 exact). cols tid, tid+512
        const int c0 = tid, c1 = tid + 512;
        float a0[2], a1[2];
        const float bb0 = b_ih[c0] + b_hh[c0];
        const float bb1 = b_ih[c1] + b_hh[c1];
        a0[0] = bb0; a0[1] = bb0; a1[0] = bb1; a1[1] = bb1;
        for (int k = 0; k < 256; k += 4) {
            const float4 w0 = *(const float4*)(w_ih + c0 * 256 + k);
            const float4 w1 = *(const float4*)(w_ih + c1 * 256 + k);
            #pragma unroll
            for (int r = 0; r < 2; ++r) {
                const float4 h = *(const float4*)(h0f + r * 256 + k);
                a0[r] += w0.x * h.x + w0.y * h.y + w0.z * h.z + w0.w * h.w;
                a1[r] += w1.x * h.x + w1.y * h.y + w1.z * h.z + w1.w * h.w;
            }
        }
        #pragma unroll
        for (int r = 0; r < 2; ++r) {
            xps[r * 1024 + c0] = a0[r];
            xps[r * 1024 + c1] = a1[r];
        }
    }
    __syncthreads();

    // each lane keeps ONLY its own 4 x_proj values.
    // gv = mfma(acc=0) + xp_own at extraction (additive, +-1ulp reorder).
    float xp_own[4];
    #pragma unroll
    for (int g = 0; g < 4; ++g)
        xp_own[g] = xps[rb * 1024 + g * 256 + mycol];
    __syncthreads();

    // ====== weights: 40 reg frags + 13 LDS frags (stream 11 stay in L2) ======
    v8bf wreg[40];
    {
        const uint4* src = (const uint4*)wbf2;
        #pragma unroll
        for (int g = 0; g < 4; ++g)
            #pragma unroll
            for (int ks = 0; ks < 8; ++ks) {      // jt0 -> reg 0..31
                const int FR = wv * 64 + g * 8 + ks;
                union { uint4 u; v8bf v; } t; t.u = src[FR * 64 + lane];
                wreg[g * 8 + ks] = t.v;
            }
        #pragma unroll
        for (int k = 0; k < 8; ++k) {             // jt1 g0 ks0..7 -> reg 32..39
            const int FR = wv * 64 + 32 + k;
            union { uint4 u; v8bf v; } t; t.u = src[FR * 64 + lane];
            wreg[32 + k] = t.v;
        }
        uint4* wl = (uint4*)WL;
        #pragma unroll
        for (int i = 0; i < 13; ++i) {            // jt1 offsets 8..20 -> LDS slots
            const int FR = wv * 64 + 32 + 8 + i;
            wl[(wv * 13 + i) * 64 + lane] = src[FR * 64 + lane];
        }
    }

    float cst = 0.0f;
    const v4f z4 = {0.0f, 0.0f, 0.0f, 0.0f};
    const __hip_bfloat16* sbase = wbf2 + (size_t)(wv * 64 + 32) * 512 + lane * 8;
    const __hip_bfloat16* wlbase = (const __hip_bfloat16*)WL + (size_t)(wv * 13) * 512 + lane * 8;
    __hip_bfloat16* hsp = hsb + (size_t)(b_base + rb) * 131072 + mycol;

    __syncthreads();

    // ================= 512 recurrent steps =================
    for (int t = 0; t < 512; ++t) {
        const __hip_bfloat16* A = hA + (t & 1) * (16 * STR);
        v4f acc[2][4];

        #pragma unroll
        for (int ks = 0; ks < 8; ++ks) {
            // A row l15&1 -> effective A[j] = h[j&1] for all j; 8 distinct 16B
            // segments/wave (broadcast), conflict-free.
            const v8bf a = *(const v8bf*)(A + (l15 & 1) * STR + ks * 32 + quad * 8);
            #pragma unroll
            for (int g = 0; g < 4; ++g) {
                // jt = 0 (always register-resident), acc init = 0
                acc[0][g] = __builtin_amdgcn_mfma_f32_16x16x32_bf16(
                    a, wreg[g * 8 + ks], (ks == 0) ? z4 : acc[0][g], 0, 0, 0);
                // jt = 1 (reg / LDS / L2-stream per table)
                v8bf w;
                if (K1[g][ks] == 0)      w = wreg[X1[g][ks]];
                else if (K1[g][ks] == 1) w = *(const v8bf*)(wlbase + X1[g][ks] * 512);
                else                     w = *(const v8bf*)(sbase + (g * 8 + ks) * 512);
                acc[1][g] = __builtin_amdgcn_mfma_f32_16x16x32_bf16(
                    a, w, (ks == 0) ? z4 : acc[1][g], 0, 0, 0);
            }
        }

        // extract own element: LITERAL vector indices + value selects
        // (v_cndmask, register-resident), then add x_proj contribution.
        float gv[4];
        #pragma unroll
        for (int g = 0; g < 4; ++g) {
            const float r0 = myjt ? acc[1][g][0] : acc[0][g][0];
            const float r1 = myjt ? acc[1][g][1] : acc[0][g][1];
            gv[g] = (rb ? r1 : r0) + xp_own[g];
        }

        // gate math (1 h-elem/thread); h -> other LDS buffer + hs (bf16 rows)
        __hip_bfloat16* An = hA + ((t + 1) & 1) * (16 * STR);
        {
            const float iv = sigmoidf_(gv[0]);
            const float fv = sigmoidf_(gv[1]);
            const float gg = tanhf_  (gv[2]);
            const float ov = sigmoidf_(gv[3]);
            const float c  = fv * cst + iv * gg;
            cst = c;
            const __hip_bfloat16 hb = __float2bfloat16(ov * tanhf_(c));
            An[rb * STR + mycol] = hb;
            hsp[(size_t)t * 256] = hb;
        }
        // lgkm-only barrier: LDS producer/consumer ordered; no vmcnt(0) store
        // drain (hs stores have no intra-kernel consumer until the epilogue).
        asm volatile("s_waitcnt lgkmcnt(0)\n\ts_barrier" ::: "memory");
    }

    // ===== fused out-projection epilogue: block's own 1024 (b,t)-rows =====
    // All hs rows of this block were written by this block's own lanes ->
    // vmcnt(0) + block barrier makes them visible (same-CU L2 path).
    asm volatile("s_waitcnt vmcnt(0) lgkmcnt(0)" ::: "memory");
    __syncthreads();

    {
        __hip_bfloat16* tile = (__hip_bfloat16*)WL;       // [128][STR], 67.6 KB
        float* outp = (float*)hsb;
        const __hip_bfloat16* wob = owb + lane * 8;
        const size_t blkrow = (size_t)blockIdx.x * 1024;  // (b,t)-row base
        const int mbase = wv * 16;                        // 16 rows per wave

        for (int tt = 0; tt < 8; ++tt) {
            const size_t m0 = blkrow + tt * 128;
            {   // stage 128x256 bf16 rows -> LDS (before overwrite: in-place safe)
                const uint4* src = (const uint4*)(hsb + m0 * 256);
                #pragma unroll
                for (int i = 0; i < 8; ++i) {
                    const int cid = tid + i * 512;        // 0..4095 chunks of 16 B
                    const int row = cid >> 5, c8 = (cid & 31) * 8;
                    *(uint4*)&tile[row * STR + c8] = src[cid];
                }
            }
            __syncthreads();

            for (int nt = 0; nt < 8; ++nt) {
                v8bf wo[8];
                #pragma unroll
                for (int ks = 0; ks < 8; ++ks)
                    wo[ks] = *(const v8bf*)(wob + (size_t)(nt * 8 + ks) * 512);
                const float ob = out_b[nt * 16 + l15];
                v4f oacc = { ob, ob, ob, ob };
                #pragma unroll
                for (int ks = 0; ks < 8; ++ks) {
                    const v8bf a = *(const v8bf*)&tile[(mbase + l15) * STR + ks * 32 + quad * 8];
                    oacc = __builtin_amdgcn_mfma_f32_16x16x32_bf16(a, wo[ks], oacc, 0, 0, 0);
                }
                #pragma unroll
                for (int r = 0; r < 4; ++r)
                    outp[(m0 + mbase + quad * 4 + r) * 128 + nt * 16 + l15] = oacc[r];
            }
            __syncthreads();   // tile LDS reuse fence (stores go to disjoint rows)
        }
    }
}

extern "C" void kernel_launch(void* const* d_in, const int* in_sizes, int n_in,
                              void* d_out, int out_size, void* d_ws, size_t ws_size,
                              hipStream_t stream) {
    (void)in_sizes; (void)n_in; (void)out_size; (void)ws_size;
    const float* z     = (const float*)d_in[0];
    const float* fc_w  = (const float*)d_in[1];
    const float* fc_b  = (const float*)d_in[2];
    const float* w_ih  = (const float*)d_in[3];
    const float* w_hh  = (const float*)d_in[4];
    const float* b_ih  = (const float*)d_in[5];
    const float* b_hh  = (const float*)d_in[6];
    const float* out_w = (const float*)d_in[7];
    const float* out_b = (const float*)d_in[8];

    __hip_bfloat16* wbf2 = (__hip_bfloat16*)d_ws;             // 512 KB swizzled w_hh
    __hip_bfloat16* owb  = (__hip_bfloat16*)d_ws + 262144;    // 64 KB swizzled out_w

    hipLaunchKernelGGL(cvt_kernel, dim3(128), dim3(256), 0, stream, w_hh, (uint4*)wbf2);
    hipLaunchKernelGGL(cvt_ow,     dim3(16),  dim3(256), 0, stream, out_w, (uint4*)owb);
    hipLaunchKernelGGL(lstm_main,  dim3(128), dim3(512), 0, stream,
                       z, fc_w, fc_b, w_ih, b_ih, b_hh, wbf2, owb, out_b,
                       (__hip_bfloat16*)d_out);
}

// Round 16
// 789.107 us; speedup vs baseline: 1.2174x; 1.2174x over previous
//
#include <hip/hip_runtime.h>
#include <hip/hip_bf16.h>

// B=256, LATENT=64, HID=256, OUT=128, S=512. gates [i|f|g|o] -> 4H=1024.
//
// R21 = R19 reverted (best measured: 789us total; R20's fusion regressed —
// the epilogue's 64MB hs read-back is NOT L2-resident (8MB/XCD vs 4MiB L2)
// and ran as an HBM tail at 128-block occupancy: FETCH 7->121MB, +205us.
// Lesson: keep bandwidth phases in their own high-occupancy dispatch).
// lstm_main: 128 blocks x 2 rows x 512 thr (8 waves, 2/SIMD); weights
// 40 reg + 13 LDS + 11 stream (bracketed: 44 spills, R18); A row=l15&1
// dataflow (C row j = gates(batch row j&1)); literal-index + v_cndmask
// extraction + xp_own add; lgkm-only barrier. hA [2][16*STR], STR=264.
// outproj: separate 1024-block dispatch, 128-row tiles, bounds(512,4),
// pre-converted bf16 out_w frags (cvt_ow).

typedef __bf16 v8bf __attribute__((ext_vector_type(8)));
typedef float  v4f  __attribute__((ext_vector_type(4)));

__device__ __forceinline__ float sigmoidf_(float x) {
    return __builtin_amdgcn_rcpf(1.0f + __expf(-x));
}
__device__ __forceinline__ float tanhf_(float x) {
    float ax = fabsf(x);
    float e  = __expf(-2.0f * ax);
    float t  = (1.0f - e) * __builtin_amdgcn_rcpf(1.0f + e);
    return copysignf(t, x);
}

// ---- wbf2 layout: frag FR(wv,jt,g,ks) = ((wv*2+jt)*4+g)*8+ks, 1024 B each;
// lane l holds 16 B at FR*1024 + l*16 = w_hh[g*256+wv*32+jt*16+(l&15)][ks*32+(l>>4)*8 + 0..7]
__global__ void cvt_kernel(const float* __restrict__ w, uint4* __restrict__ o) {
    const int gg = blockIdx.x * 256 + threadIdx.x;    // 0..32767
    const int F = gg >> 6, l = gg & 63;
    const int wv = F >> 6, rem = F & 63;
    const int jt = rem >> 5, g4 = (rem >> 3) & 3, ks = rem & 7;
    const int row = g4 * 256 + wv * 32 + jt * 16 + (l & 15);
    const int col = ks * 32 + (l >> 4) * 8;
    const float4 a = *(const float4*)(w + row * 256 + col);
    const float4 b = *(const float4*)(w + row * 256 + col + 4);
    union { __hip_bfloat16 h[8]; uint4 u; } p;
    p.h[0] = __float2bfloat16(a.x); p.h[1] = __float2bfloat16(a.y);
    p.h[2] = __float2bfloat16(a.z); p.h[3] = __float2bfloat16(a.w);
    p.h[4] = __float2bfloat16(b.x); p.h[5] = __float2bfloat16(b.y);
    p.h[6] = __float2bfloat16(b.z); p.h[7] = __float2bfloat16(b.w);
    o[gg] = p.u;
}

// ---- owb layout: frag F(nt,ks) = nt*8+ks, 1024 B each; lane l holds
// out_w[nt*16+(l&15)][ks*32+(l>>4)*8 + 0..7] -> outproj B-operand direct.
__global__ void cvt_ow(const float* __restrict__ w, uint4* __restrict__ o) {
    const int gg = blockIdx.x * 256 + threadIdx.x;    // 0..4095
    const int F = gg >> 6, l = gg & 63;
    const int nt = F >> 3, ks = F & 7;
    const int row = nt * 16 + (l & 15);
    const int col = ks * 32 + (l >> 4) * 8;
    const float4 a = *(const float4*)(w + row * 256 + col);
    const float4 b = *(const float4*)(w + row * 256 + col + 4);
    union { __hip_bfloat16 h[8]; uint4 u; } p;
    p.h[0] = __float2bfloat16(a.x); p.h[1] = __float2bfloat16(a.y);
    p.h[2] = __float2bfloat16(a.z); p.h[3] = __float2bfloat16(a.w);
    p.h[4] = __float2bfloat16(b.x); p.h[5] = __float2bfloat16(b.y);
    p.h[6] = __float2bfloat16(b.z); p.h[7] = __float2bfloat16(b.w);
    o[gg] = p.u;
}

constexpr int STR = 264;                 // hA row stride (bf16 elems)

// jt==1 weight source tables: kind 0=reg,1=lds,2=stream  (R17 placement)
// jt1 frag offsets 0..31 = g*8+ks.
//   reg:    offsets 0..7  (g0 all)            -> wreg 32..39
//   LDS:    offsets 8..20 (g1 all, g2 ks0..4) -> slots 0..12
//   stream: offsets 21..31 (g2 ks5..7, g3 all)
__device__ constexpr int K1[4][8] = {
    {0,0,0,0, 0,0,0,0},
    {1,1,1,1, 1,1,1,1},
    {1,1,1,1, 1,2,2,2},
    {2,2,2,2, 2,2,2,2},
};
__device__ constexpr int X1[4][8] = {
    {32,33,34,35, 36,37,38,39},
    { 0, 1, 2, 3,  4, 5, 6, 7},
    { 8, 9,10,11, 12, 0, 0, 0},
    { 0, 0, 0, 0,  0, 0, 0, 0},
};

__global__ __launch_bounds__(512, 2) void lstm_main(
    const float* __restrict__ z,     const float* __restrict__ fc_w,
    const float* __restrict__ fc_b,  const float* __restrict__ w_ih,
    const float* __restrict__ b_ih,  const float* __restrict__ b_hh,
    const __hip_bfloat16* __restrict__ wbf2,
    __hip_bfloat16* __restrict__ hsb)           // = d_out viewed as bf16 [B*512][256]
{
    __shared__ __align__(16) unsigned char SM[16896 + 139264];
    __hip_bfloat16* hA = (__hip_bfloat16*)SM;             // [2][16*STR]
    unsigned char*  WL = SM + 16896;                      // weight LDS / prologue alias

    const int tid  = threadIdx.x;
    const int wv   = tid >> 6;       // 0..7
    const int lane = tid & 63;
    const int l15  = lane & 15;
    const int quad = lane >> 4;
    const int b_base = blockIdx.x * 2;                    // 2 batch rows / block

    // ownership: lane handles exactly 1 h-elem (row rb, col mycol), jt=quad>>1
    const int rb    = quad & 1;                           // even quads row 0, odd row 1
    const int myjt  = quad >> 1;
    const int mycol = wv * 32 + myjt * 16 + l15;

    // ================= prologue (aliased LDS) =================
    float* h0f = (float*)WL;               // [2][256]   2 KB used
    float* xps = (float*)(WL + 16384);     // [2][1024]  8 KB used
    float* zt  = (float*)(WL + 81920);     // [2][64]   0.5 KB used

    {   // z tile: 2 rows x 64 (hA rows 2..15 are dead -> no zero-init needed)
        if (tid < 128) zt[tid] = z[b_base * 64 + tid];
    }
    __syncthreads();

    {   // h0 = z @ fc_w.T + fc_b  (fp32 exact). thread: col=tid&255, row=tid>>8
        const int col = tid & 255;
        const int r   = tid >> 8;                         // 0 or 1
        float a = fc_b[col];
        for (int k = 0; k < 64; k += 4) {
            const float4 w = *(const float4*)(fc_w + col * 64 + k);
            const float4 h = *(const float4*)(zt + r * 64 + k);
            a += w.x * h.x + w.y * h.y + w.z * h.z + w.w * h.w;
        }
        h0f[r * 256 + col] = a;
        hA[r * STR + col] = __float2bfloat16(a);
    }
    __syncthreads();

    {   // x_proj = h0 @ w_ih.T + (b_ih + b_hh)  (fp32 exact). cols tid, tid+512
        const int c0 = tid, c1 = tid + 512;
        float a0[2], a1[2];
        const float bb0 = b_ih[c0] + b_hh[c0];
        const float bb1 = b_ih[c1] + b_hh[c1];
        a0[0] = bb0; a0[1] = bb0; a1[0] = bb1; a1[1] = bb1;
        for (int k = 0; k < 256; k += 4) {
            const float4 w0 = *(const float4*)(w_ih + c0 * 256 + k);
            const float4 w1 = *(const float4*)(w_ih + c1 * 256 + k);
            #pragma unroll
            for (int r = 0; r < 2; ++r) {
                const float4 h = *(const float4*)(h0f + r * 256 + k);
                a0[r] += w0.x * h.x + w0.y * h.y + w0.z * h.z + w0.w * h.w;
                a1[r] += w1.x * h.x + w1.y * h.y + w1.z * h.z + w1.w * h.w;
            }
        }
        #pragma unroll
        for (int r = 0; r < 2; ++r) {
            xps[r * 1024 + c0] = a0[r];
            xps[r * 1024 + c1] = a1[r];
        }
    }
    __syncthreads();

    // each lane keeps ONLY its own 4 x_proj values.
    // gv = mfma(acc=0) + xp_own at extraction (additive, +-1ulp reorder).
    float xp_own[4];
    #pragma unroll
    for (int g = 0; g < 4; ++g)
        xp_own[g] = xps[rb * 1024 + g * 256 + mycol];
    __syncthreads();

    // ====== weights: 40 reg frags + 13 LDS frags (stream 11 stay in L2) ======
    v8bf wreg[40];
    {
        const uint4* src = (const uint4*)wbf2;
        #pragma unroll
        for (int g = 0; g < 4; ++g)
            #pragma unroll
            for (int ks = 0; ks < 8; ++ks) {      // jt0 -> reg 0..31
                const int FR = wv * 64 + g * 8 + ks;
                union { uint4 u; v8bf v; } t; t.u = src[FR * 64 + lane];
                wreg[g * 8 + ks] = t.v;
            }
        #pragma unroll
        for (int k = 0; k < 8; ++k) {             // jt1 g0 ks0..7 -> reg 32..39
            const int FR = wv * 64 + 32 + k;
            union { uint4 u; v8bf v; } t; t.u = src[FR * 64 + lane];
            wreg[32 + k] = t.v;
        }
        uint4* wl = (uint4*)WL;
        #pragma unroll
        for (int i = 0; i < 13; ++i) {            // jt1 offsets 8..20 -> LDS slots
            const int FR = wv * 64 + 32 + 8 + i;
            wl[(wv * 13 + i) * 64 + lane] = src[FR * 64 + lane];
        }
    }

    float cst = 0.0f;
    const v4f z4 = {0.0f, 0.0f, 0.0f, 0.0f};
    const __hip_bfloat16* sbase = wbf2 + (size_t)(wv * 64 + 32) * 512 + lane * 8;
    const __hip_bfloat16* wlbase = (const __hip_bfloat16*)WL + (size_t)(wv * 13) * 512 + lane * 8;
    __hip_bfloat16* hsp = hsb + (size_t)(b_base + rb) * 131072 + mycol;

    __syncthreads();

    // ================= 512 recurrent steps =================
    for (int t = 0; t < 512; ++t) {
        const __hip_bfloat16* A = hA + (t & 1) * (16 * STR);
        v4f acc[2][4];

        #pragma unroll
        for (int ks = 0; ks < 8; ++ks) {
            // A row l15&1 -> effective A[j] = h[j&1] for all j; 8 distinct 16B
            // segments/wave (broadcast), conflict-free.
            const v8bf a = *(const v8bf*)(A + (l15 & 1) * STR + ks * 32 + quad * 8);
            #pragma unroll
            for (int g = 0; g < 4; ++g) {
                // jt = 0 (always register-resident), acc init = 0
                acc[0][g] = __builtin_amdgcn_mfma_f32_16x16x32_bf16(
                    a, wreg[g * 8 + ks], (ks == 0) ? z4 : acc[0][g], 0, 0, 0);
                // jt = 1 (reg / LDS / L2-stream per table)
                v8bf w;
                if (K1[g][ks] == 0)      w = wreg[X1[g][ks]];
                else if (K1[g][ks] == 1) w = *(const v8bf*)(wlbase + X1[g][ks] * 512);
                else                     w = *(const v8bf*)(sbase + (g * 8 + ks) * 512);
                acc[1][g] = __builtin_amdgcn_mfma_f32_16x16x32_bf16(
                    a, w, (ks == 0) ? z4 : acc[1][g], 0, 0, 0);
            }
        }

        // extract own element: LITERAL vector indices + value selects
        // (v_cndmask, register-resident), then add x_proj contribution.
        float gv[4];
        #pragma unroll
        for (int g = 0; g < 4; ++g) {
            const float r0 = myjt ? acc[1][g][0] : acc[0][g][0];
            const float r1 = myjt ? acc[1][g][1] : acc[0][g][1];
            gv[g] = (rb ? r1 : r0) + xp_own[g];
        }

        // gate math (1 h-elem/thread); h -> other LDS buffer + hs (bf16 rows)
        __hip_bfloat16* An = hA + ((t + 1) & 1) * (16 * STR);
        {
            const float iv = sigmoidf_(gv[0]);
            const float fv = sigmoidf_(gv[1]);
            const float gg = tanhf_  (gv[2]);
            const float ov = sigmoidf_(gv[3]);
            const float c  = fv * cst + iv * gg;
            cst = c;
            const __hip_bfloat16 hb = __float2bfloat16(ov * tanhf_(c));
            An[rb * STR + mycol] = hb;
            hsp[(size_t)t * 256] = hb;
        }
        // lgkm-only barrier: LDS producer/consumer ordered; no vmcnt(0) store
        // drain (hs stores have no intra-kernel consumer, addresses unique).
        asm volatile("s_waitcnt lgkmcnt(0)\n\ts_barrier" ::: "memory");
    }
}

// ---- out-projection, in place over d_out: reads bf16 hs rows, writes fp32 out ----
// 1024 blocks x 128 rows; 67.6KB LDS + launch_bounds(512,4) -> 2 blocks/CU
// co-resident (stage/compute overlap); full-chip occupancy for the 64MB HBM
// re-read (R20 lesson: this phase must NOT live in the 128-block kernel).
__global__ __launch_bounds__(512, 4) void outproj_kernel(
    void* __restrict__ io, const __hip_bfloat16* __restrict__ owb,
    const float* __restrict__ out_b)
{
    __shared__ __hip_bfloat16 tile[128 * STR];            // 128 rows x 264, 67584 B
    const __hip_bfloat16* hsb = (const __hip_bfloat16*)io;
    float* outp = (float*)io;

    const int tid  = threadIdx.x;
    const int wv   = tid >> 6;       // 0..7
    const int lane = tid & 63;
    const int l15  = lane & 15;
    const int quad = lane >> 4;
    const int m0   = blockIdx.x * 128;                    // (b,t) row base

    // stage 128x256 bf16 rows -> LDS (before any write: in-place safe)
    {
        const uint4* src = (const uint4*)(hsb + (size_t)m0 * 256);
        #pragma unroll
        for (int i = 0; i < 8; ++i) {
            const int cid = tid + i * 512;                // 0..4095 chunks of 16 B
            const int row = cid >> 5, c8 = (cid & 31) * 8;
            *(uint4*)&tile[row * STR + c8] = src[cid];
        }
    }
    __syncthreads();

    const int mbase = wv * 16;                            // 16 rows per wave
    const __hip_bfloat16* wob = owb + lane * 8;
    for (int nt = 0; nt < 8; ++nt) {
        v8bf wo[8];
        #pragma unroll
        for (int ks = 0; ks < 8; ++ks)
            wo[ks] = *(const v8bf*)(wob + (size_t)(nt * 8 + ks) * 512);
        const float ob = out_b[nt * 16 + l15];
        v4f oacc = { ob, ob, ob, ob };
        #pragma unroll
        for (int ks = 0; ks < 8; ++ks) {
            const v8bf a = *(const v8bf*)&tile[(mbase + l15) * STR + ks * 32 + quad * 8];
            oacc = __builtin_amdgcn_mfma_f32_16x16x32_bf16(a, wo[ks], oacc, 0, 0, 0);
        }
        #pragma unroll
        for (int r = 0; r < 4; ++r)
            outp[(size_t)(m0 + mbase + quad * 4 + r) * 128 + nt * 16 + l15] = oacc[r];
    }
}

extern "C" void kernel_launch(void* const* d_in, const int* in_sizes, int n_in,
                              void* d_out, int out_size, void* d_ws, size_t ws_size,
                              hipStream_t stream) {
    (void)in_sizes; (void)n_in; (void)out_size; (void)ws_size;
    const float* z     = (const float*)d_in[0];
    const float* fc_w  = (const float*)d_in[1];
    const float* fc_b  = (const float*)d_in[2];
    const float* w_ih  = (const float*)d_in[3];
    const float* w_hh  = (const float*)d_in[4];
    const float* b_ih  = (const float*)d_in[5];
    const float* b_hh  = (const float*)d_in[6];
    const float* out_w = (const float*)d_in[7];
    const float* out_b = (const float*)d_in[8];

    __hip_bfloat16* wbf2 = (__hip_bfloat16*)d_ws;             // 512 KB swizzled w_hh
    __hip_bfloat16* owb  = (__hip_bfloat16*)d_ws + 262144;    // 64 KB swizzled out_w

    hipLaunchKernelGGL(cvt_kernel, dim3(128), dim3(256), 0, stream, w_hh, (uint4*)wbf2);
    hipLaunchKernelGGL(cvt_ow,     dim3(16),  dim3(256), 0, stream, out_w, (uint4*)owb);
    hipLaunchKernelGGL(lstm_main,  dim3(128), dim3(512), 0, stream,
                       z, fc_w, fc_b, w_ih, b_ih, b_hh, wbf2, (__hip_bfloat16*)d_out);
    hipLaunchKernelGGL(outproj_kernel, dim3(1024), dim3(512), 0, stream,
                       d_out, owb, out_b);
}